// Round 4
// baseline (579.059 us; speedup 1.0000x reference)
//
#include <hip/hip_runtime.h>
#include <hip/hip_bf16.h>
#include <cstdint>
#include <cstddef>

#define S_LEN 512
#define BATCH 32
#define EDIM  300
#define KPAD  320
#define K3    960   // [Xh|Xh|Xl] / [Wh|Wl|Wh]
#define HDIM  128
#define NGATE 512   // 4*H
#define NCOLS 1024  // fwd 512 + bwd 512

typedef float    f2   __attribute__((ext_vector_type(2)));
typedef float    f4v  __attribute__((ext_vector_type(4)));
typedef short    short8 __attribute__((ext_vector_type(8)));
typedef _Float16 h2   __attribute__((ext_vector_type(2)));
typedef _Float16 half8 __attribute__((ext_vector_type(8)));

// DPP cross-lane move (VALU pipe). row rotates: 0x124 = row_ror:4,
// 0x128 = row_ror:8 (verified R1-R7 of prior session + v6/v8 here).
template <int CTRL>
__device__ __forceinline__ float dpp_mov(float x) {
    int r = __builtin_amdgcn_update_dpp(0, __float_as_int(x), CTRL, 0xF, 0xF, true);
    return __int_as_float(r);
}

// pack two f32 -> f16x2 (v_cvt_pkrtz_f16_f32)
__device__ __forceinline__ h2 pk_f16(float a, float b) {
    auto r = __builtin_amdgcn_cvt_pkrtz(a, b);
    return __builtin_bit_cast(h2, r);
}

__device__ __forceinline__ void bf16_split(float v, ushort& hi, ushort& lo) {
    __hip_bfloat16 hb = __float2bfloat16(v);
    float hf = __bfloat162float(hb);
    __hip_bfloat16 lb = __float2bfloat16(v - hf);
    hi = *reinterpret_cast<ushort*>(&hb);
    lo = *reinterpret_cast<ushort*>(&lb);
}

// ---------------------------------------------------------------------------
// Kernel 1: embeddings -> Xcat (bf16 hi/lo split), row = [Xh | Xh | Xl]
// ---------------------------------------------------------------------------
__global__ void embed_xcat(const int* __restrict__ word_ids,
                           const int* __restrict__ deps_ids,
                           const float* __restrict__ word_table,
                           const float* __restrict__ dep_table,
                           ushort* __restrict__ Xcat) {
    int pos = blockIdx.x;
    int b = pos >> 9, s = pos & (S_LEN - 1);
    int wid = word_ids[b * 3 * S_LEN + S_LEN + s];
    const int* dp = deps_ids + (size_t)pos * 8;
    int ids[8];
    int cnt = 0;
#pragma unroll
    for (int d = 0; d < 8; ++d) {
        int id = dp[d];
        ids[d] = id;
        cnt += (id != 0 && id != 1) ? 1 : 0;
    }
    float inv = 0.5f / (float)((cnt > 0) ? cnt : 1);
    const float* wr = word_table + (size_t)wid * EDIM;
    ushort* xr = Xcat + (size_t)pos * K3;
    for (int e = threadIdx.x; e < KPAD; e += 128) {
        float v = 0.f;
        if (e < EDIM) {
            float w = wr[e];
            float dsum = 0.f;
#pragma unroll
            for (int d = 0; d < 8; ++d) {
                if (ids[d] != 0 && ids[d] != 1) dsum += dep_table[ids[d] * EDIM + e];
            }
            v = (cnt > 0) ? (0.5f * w + dsum * inv) : w;
        }
        ushort hu, lu;
        bf16_split(v, hu, lu);
        xr[e] = hu;
        xr[KPAD + e] = hu;
        xr[2 * KPAD + e] = lu;
    }
}

// ---------------------------------------------------------------------------
// Kernel 1b: Wih -> Wcat, row n = [Wh | Wl | Wh]
// ---------------------------------------------------------------------------
__global__ void wcat_kernel(const float* __restrict__ Wih_f,
                            const float* __restrict__ Wih_b,
                            ushort* __restrict__ Wcat) {
    int n = blockIdx.x;
    const float* src = (n < NGATE) ? (Wih_f + (size_t)n * EDIM)
                                   : (Wih_b + (size_t)(n - NGATE) * EDIM);
    ushort* wr = Wcat + (size_t)n * K3;
    for (int e = threadIdx.x; e < KPAD; e += 128) {
        float v = (e < EDIM) ? src[e] : 0.f;
        ushort hu, lu;
        bf16_split(v, hu, lu);
        wr[e] = hu;
        wr[KPAD + e] = lu;
        wr[2 * KPAD + e] = hu;
    }
}

// ---------------------------------------------------------------------------
// Kernel 2: MFMA GEMM (bf16x3), unchanged (verified).
// ---------------------------------------------------------------------------
#define LSTR 40
__global__ __launch_bounds__(256) void gemm_mfma(
        const ushort* __restrict__ Xcat,
        const ushort* __restrict__ Wcat,
        const float* __restrict__ b_f, const float* __restrict__ b_b,
        float* __restrict__ pre) {
    __shared__ ushort Asub[128 * LSTR];
    __shared__ ushort Bsub[128 * LSTR];
    int tid = threadIdx.x;
    int wave = tid >> 6, lane = tid & 63;
    int lid = lane & 15, quad = lane >> 4;
    int m0 = blockIdx.x * 128, n0 = blockIdx.y * 128;
    int wm = (wave >> 1) * 64, wn = (wave & 1) * 64;

    f4v acc[4][4];
#pragma unroll
    for (int i = 0; i < 4; ++i)
#pragma unroll
        for (int j = 0; j < 4; ++j) acc[i][j] = (f4v)0.f;

    float bias[4];
#pragma unroll
    for (int nt = 0; nt < 4; ++nt) {
        int n = n0 + wn + nt * 16 + lid;
        bias[nt] = (n < NGATE) ? b_f[n] : b_b[n - NGATE];
    }

    int c0 = tid, c1 = tid + 256;
    const ushort* aptr0 = Xcat + (size_t)(m0 + (c0 >> 2)) * K3 + (c0 & 3) * 8;
    const ushort* aptr1 = Xcat + (size_t)(m0 + (c1 >> 2)) * K3 + (c1 & 3) * 8;
    const ushort* bptr0 = Wcat + (size_t)(n0 + (c0 >> 2)) * K3 + (c0 & 3) * 8;
    const ushort* bptr1 = Wcat + (size_t)(n0 + (c1 >> 2)) * K3 + (c1 & 3) * 8;
    int la0 = (c0 >> 2) * LSTR + (c0 & 3) * 8;
    int la1 = (c1 >> 2) * LSTR + (c1 & 3) * 8;

    short8 ra0 = *(const short8*)(aptr0);
    short8 ra1 = *(const short8*)(aptr1);
    short8 rb0 = *(const short8*)(bptr0);
    short8 rb1 = *(const short8*)(bptr1);

    for (int k0 = 0; k0 < K3; k0 += 32) {
        __syncthreads();
        *(short8*)&Asub[la0] = ra0;
        *(short8*)&Asub[la1] = ra1;
        *(short8*)&Bsub[la0] = rb0;
        *(short8*)&Bsub[la1] = rb1;
        __syncthreads();
        if (k0 + 32 < K3) {
            ra0 = *(const short8*)(aptr0 + k0 + 32);
            ra1 = *(const short8*)(aptr1 + k0 + 32);
            rb0 = *(const short8*)(bptr0 + k0 + 32);
            rb1 = *(const short8*)(bptr1 + k0 + 32);
        }
        short8 aF[4], bF[4];
#pragma unroll
        for (int mt = 0; mt < 4; ++mt)
            aF[mt] = *(const short8*)&Asub[(wm + mt * 16 + lid) * LSTR + quad * 8];
#pragma unroll
        for (int nt = 0; nt < 4; ++nt)
            bF[nt] = *(const short8*)&Bsub[(wn + nt * 16 + lid) * LSTR + quad * 8];
#pragma unroll
        for (int mt = 0; mt < 4; ++mt)
#pragma unroll
            for (int nt = 0; nt < 4; ++nt)
                acc[mt][nt] = __builtin_amdgcn_mfma_f32_16x16x32_bf16(
                    aF[mt], bF[nt], acc[mt][nt], 0, 0, 0);
    }

#pragma unroll
    for (int mt = 0; mt < 4; ++mt)
#pragma unroll
        for (int nt = 0; nt < 4; ++nt) {
            int n = n0 + wn + nt * 16 + lid;
#pragma unroll
            for (int r = 0; r < 4; ++r) {
                int m = m0 + wm + mt * 16 + quad * 4 + r;
                pre[(size_t)m * NCOLS + n] = acc[mt][nt][r] + bias[nt];
            }
        }
}

// ---------------------------------------------------------------------------
// Kernel 3: LSTM recurrence v9 — MFMA-based recurrent GEMV.
// 64 blocks (b,dir) x 256 threads (4 waves, 1/SIMD).
// Per wave: 128 gate rows r = tau*32 + q (tau=r>>5, q=r&31), abs Whh row
// g = tau*128 + 32*wv + q.  Per step: D = A(W rows, f16) x B(h bcast to all
// 16 cols, f16): 8 m-tiles x 4 k-tiles = 32 mfma_f32_16x16x32_f16.
// B-frag: lane reads h[32kt + 8*quad .. +8] (one ds_read_b128 per kt).
// D layout (m89-verified, also used by gemm_mfma epilogue): lane holds rows
// 16mt + 4*quad + reg, uniform over lane&15 (B cols identical).
// Lane n=l&15 owns gate pair: mt=n>>1, regs (n&1)*2+{0,1} ->
//   r = 16(n>>1)+4q+2(n&1)+{0,1};  tau = n>>2,
//   q0 = 16*((n>>1)&1) + 4*quad + 2*(n&1)  (even), pair = (tau,q0),(tau,q0+1).
// Selection: 30-cndmask static tree.  Activation per lane (both gates are
// type tau): e=exp(g*mult), act=fma(rcp(1+e),sA,sB) — exact v6 math.
// i/f/g/o gather for q0,q0+1: tau-owners are lanes n+-4k (same q0);
// masked-sum via verified ror:4+ror:8 reduce (direction-proof).
// Every lane runs both c-chains; tau==0 lanes write packed h2 + pooled f2.
// Barrier: raw builtin lgkmcnt(0)+s_barrier pinned by sched_barrier(0) —
// no vmcnt drain, pre prefetch stays in flight (m201/m218 pattern).
// ---------------------------------------------------------------------------
__global__ __launch_bounds__(256, 1) void lstm_rec(
        const float* __restrict__ pre,
        const float* __restrict__ Whh_f, const float* __restrict__ Whh_b,
        float* __restrict__ pooled) {
    __shared__ __align__(16) _Float16 h_s[HDIM];
    int t = threadIdx.x;
    int lane = t & 63;
    int wv = t >> 6;
    int n = lane & 15;
    int quad = lane >> 4;
    int tau = n >> 2;
    int q0 = ((n >> 1) & 1) * 16 + quad * 4 + (n & 1) * 2;
    int b = blockIdx.x >> 1;
    int dir = blockIdx.x & 1;
    const float* Whh = dir ? Whh_b : Whh_f;

    // A-fragments: afr[mt][kt] = Whh[g(16mt+n)][32kt + 8*quad .. +8] as f16.
    half8 afr[8][4];
#pragma unroll
    for (int mt = 0; mt < 8; ++mt) {
#pragma unroll
        for (int kt = 0; kt < 4; ++kt) {
            int r = 16 * mt + n;
            int g = (r >> 5) * HDIM + 32 * wv + (r & 31);
            const float* rp = Whh + (size_t)g * HDIM + 32 * kt + 8 * quad;
            half8 hv;
#pragma unroll
            for (int e = 0; e < 8; ++e) hv[e] = (_Float16)rp[e];
            afr[mt][kt] = hv;
        }
    }

    const f4v zero4 = (f4v)0.f;
    float cX = 0.f, cY = 0.f;
    float hmX = -1e30f, hmY = -1e30f;
    if (t < 64) ((uint*)h_s)[t] = 0u;       // zero 128 f16

    bool is_g = (tau == 2);
    float mult = is_g ? -2.f : -1.f;        // sigm: e^-g ; tanh: e^-2g
    float sA   = is_g ?  2.f :  1.f;        // act = fma(rcp, sA, sB)
    float sB   = is_g ? -1.f :  0.f;

    // pre columns for the owned pair (adjacent -> f2 loads)
    const f2* pz = (const f2*)(pre + (size_t)b * S_LEN * NCOLS + dir * NGATE
                               + tau * HDIM + 32 * wv + q0);
    int s = dir ? (S_LEN - 1) : 0;
    int sd = dir ? -1 : 1;
    f2 pn1 = pz[(long)s * 512];
    f2 pn2 = pz[(long)(s + sd) * 512];

    int hw = (32 * wv + q0) >> 1;           // h2 index this lane's pair writes

    __builtin_amdgcn_sched_barrier(0);
    __builtin_amdgcn_s_waitcnt(0xC07F);     // lgkmcnt(0) only
    __builtin_amdgcn_s_barrier();
    __builtin_amdgcn_sched_barrier(0);

    for (int step = 0; step < S_LEN; ++step) {
        f2 cur = pn1;
        pn1 = pn2;
        if (step + 2 < S_LEN) pn2 = pz[(long)(s + 2 * sd) * 512];

        // B-fragments: h chunk per quad, per k-tile (4 x ds_read_b128)
        half8 bf0 = *(const half8*)&h_s[ 0 + 8 * quad];
        half8 bf1 = *(const half8*)&h_s[32 + 8 * quad];
        half8 bf2 = *(const half8*)&h_s[64 + 8 * quad];
        half8 bf3 = *(const half8*)&h_s[96 + 8 * quad];

        // 8 acc chains x 4 k-tiles = 32 MFMA
        f4v acc[8];
#pragma unroll
        for (int mt = 0; mt < 8; ++mt)
            acc[mt] = __builtin_amdgcn_mfma_f32_16x16x32_f16(afr[mt][0], bf0, zero4, 0, 0, 0);
#pragma unroll
        for (int mt = 0; mt < 8; ++mt)
            acc[mt] = __builtin_amdgcn_mfma_f32_16x16x32_f16(afr[mt][1], bf1, acc[mt], 0, 0, 0);
#pragma unroll
        for (int mt = 0; mt < 8; ++mt)
            acc[mt] = __builtin_amdgcn_mfma_f32_16x16x32_f16(afr[mt][2], bf2, acc[mt], 0, 0, 0);
#pragma unroll
        for (int mt = 0; mt < 8; ++mt)
            acc[mt] = __builtin_amdgcn_mfma_f32_16x16x32_f16(afr[mt][3], bf3, acc[mt], 0, 0, 0);

        // static selection tree: dotX/dotY = acc[n>>1][(n&1)*2 + {0,1}]
        float sX[8], sY[8];
#pragma unroll
        for (int mt = 0; mt < 8; ++mt) {
            sX[mt] = (n & 1) ? acc[mt][2] : acc[mt][0];
            sY[mt] = (n & 1) ? acc[mt][3] : acc[mt][1];
        }
        float xa = (n & 2) ? sX[1] : sX[0];
        float xb = (n & 2) ? sX[3] : sX[2];
        float xc = (n & 2) ? sX[5] : sX[4];
        float xd = (n & 2) ? sX[7] : sX[6];
        float ya = (n & 2) ? sY[1] : sY[0];
        float yb = (n & 2) ? sY[3] : sY[2];
        float yc = (n & 2) ? sY[5] : sY[4];
        float yd = (n & 2) ? sY[7] : sY[6];
        float xe = (n & 4) ? xb : xa;
        float xf = (n & 4) ? xd : xc;
        float ye = (n & 4) ? yb : ya;
        float yf = (n & 4) ? yd : yc;
        float dotX = (n & 8) ? xf : xe;
        float dotY = (n & 8) ? yf : ye;

        float gX = dotX + cur[0];
        float gY = dotY + cur[1];

        // per-lane activation (both gates type tau): exact v6 math
        float eX = __expf(gX * mult);
        float eY = __expf(gY * mult);
        float rX = __builtin_amdgcn_rcpf(1.f + eX);
        float rY = __builtin_amdgcn_rcpf(1.f + eY);
        float actX = fmaf(rX, sA, sB);
        float actY = fmaf(rY, sA, sB);

        // i/f/g/o gather: masked-sum over the 4 tau-owner lanes (n +- 4k),
        // via the verified ror:4 + ror:8 full-group reduce.
        float miX = (tau == 0) ? actX : 0.f;
        float mfX = (tau == 1) ? actX : 0.f;
        float mgX = (tau == 2) ? actX : 0.f;
        float moX = (tau == 3) ? actX : 0.f;
        float miY = (tau == 0) ? actY : 0.f;
        float mfY = (tau == 1) ? actY : 0.f;
        float mgY = (tau == 2) ? actY : 0.f;
        float moY = (tau == 3) ? actY : 0.f;
        miX += dpp_mov<0x124>(miX); miX += dpp_mov<0x128>(miX);
        mfX += dpp_mov<0x124>(mfX); mfX += dpp_mov<0x128>(mfX);
        mgX += dpp_mov<0x124>(mgX); mgX += dpp_mov<0x128>(mgX);
        moX += dpp_mov<0x124>(moX); moX += dpp_mov<0x128>(moX);
        miY += dpp_mov<0x124>(miY); miY += dpp_mov<0x128>(miY);
        mfY += dpp_mov<0x124>(mfY); mfY += dpp_mov<0x128>(mfY);
        mgY += dpp_mov<0x124>(mgY); mgY += dpp_mov<0x128>(mgY);
        moY += dpp_mov<0x124>(moY); moY += dpp_mov<0x128>(moY);

        // both c-chains on every owner lane (redundant x4, keeps lanes busy)
        cX = fmaf(mfX, cX, miX * mgX);
        cY = fmaf(mfY, cY, miY * mgY);
        float ecX = __expf(-2.f * cX);
        float ecY = __expf(-2.f * cY);
        float rcX = __builtin_amdgcn_rcpf(1.f + ecX);
        float rcY = __builtin_amdgcn_rcpf(1.f + ecY);
        float hX = moX * fmaf(rcX, 2.f, -1.f);
        float hY = moY * fmaf(rcY, 2.f, -1.f);
        hmX = fmaxf(hmX, hX);
        hmY = fmaxf(hmY, hY);

        if (tau == 0) {
            h2 hv;
            hv[0] = (_Float16)hX;
            hv[1] = (_Float16)hY;
            ((h2*)h_s)[hw] = hv;
        }
        __builtin_amdgcn_sched_barrier(0);
        __builtin_amdgcn_s_waitcnt(0xC07F);  // lgkmcnt(0) only — vmcnt stays
        __builtin_amdgcn_s_barrier();
        __builtin_amdgcn_sched_barrier(0);
        s += sd;
    }

    if (tau == 0) {
        f2 pv;
        pv[0] = hmX;
        pv[1] = hmY;
        *(f2*)(pooled + b * 256 + dir * HDIM + 32 * wv + q0) = pv;
    }
}

// ---------------------------------------------------------------------------
// Kernel 4: classifier (unchanged)
// ---------------------------------------------------------------------------
__global__ void cls_kernel(const float* __restrict__ pooled,
                           const float* __restrict__ W_cls,
                           const float* __restrict__ b_cls,
                           float* __restrict__ out) {
    int i = threadIdx.x;
    if (i < BATCH * 5) {
        int b = i / 5, l = i % 5;
        float acc = b_cls[l];
        const float* p = pooled + b * 256;
        const float* w = W_cls + l * 256;
#pragma unroll 8
        for (int j = 0; j < 256; ++j) acc = fmaf(p[j], w[j], acc);
        out[i] = acc;
    }
}

// ---------------------------------------------------------------------------
extern "C" void kernel_launch(void* const* d_in, const int* in_sizes, int n_in,
                              void* d_out, int out_size, void* d_ws, size_t ws_size,
                              hipStream_t stream) {
    const int*   word_ids   = (const int*)d_in[0];
    const int*   deps_ids   = (const int*)d_in[1];
    const float* word_table = (const float*)d_in[2];
    const float* dep_table  = (const float*)d_in[3];
    const float* Wih_f      = (const float*)d_in[4];
    const float* Whh_f      = (const float*)d_in[5];
    const float* b_f        = (const float*)d_in[6];
    const float* Wih_b      = (const float*)d_in[7];
    const float* Whh_b      = (const float*)d_in[8];
    const float* b_b        = (const float*)d_in[9];
    const float* W_cls      = (const float*)d_in[10];
    const float* b_cls      = (const float*)d_in[11];
    float* out = (float*)d_out;

    float*  pre    = (float*)d_ws;
    float*  pooled = pre + (size_t)BATCH * S_LEN * NCOLS;
    ushort* Xcat   = (ushort*)(pooled + BATCH * 256);
    ushort* Wcat   = Xcat + (size_t)BATCH * S_LEN * K3;

    embed_xcat<<<BATCH * S_LEN, 128, 0, stream>>>(word_ids, deps_ids,
                                                  word_table, dep_table, Xcat);
    wcat_kernel<<<NCOLS, 128, 0, stream>>>(Wih_f, Wih_b, Wcat);
    gemm_mfma<<<dim3(128, 8), 256, 0, stream>>>(Xcat, Wcat, b_f, b_b, pre);
    lstm_rec<<<64, 256, 0, stream>>>(pre, Whh_f, Whh_b, pooled);
    cls_kernel<<<1, 192, 0, stream>>>(pooled, W_cls, b_cls, out);
}

// Round 5
// 484.964 us; speedup vs baseline: 1.1940x; 1.1940x over previous
//
#include <hip/hip_runtime.h>
#include <hip/hip_bf16.h>
#include <cstdint>
#include <cstddef>

#define S_LEN 512
#define BATCH 32
#define EDIM  300
#define KPAD  320   // single f16 pass (was 960 bf16 hi/lo x3)
#define HDIM  128
#define NGATE 512   // 4*H
#define NCOLS 1024  // fwd 512 + bwd 512

typedef float    f2   __attribute__((ext_vector_type(2)));
typedef float    f4v  __attribute__((ext_vector_type(4)));
typedef _Float16 h2   __attribute__((ext_vector_type(2)));
typedef _Float16 half8 __attribute__((ext_vector_type(8)));

// pack two f32 -> f16x2 (v_cvt_pkrtz_f16_f32)
__device__ __forceinline__ h2 pk_f16(float a, float b) {
    auto r = __builtin_amdgcn_cvt_pkrtz(a, b);
    return __builtin_bit_cast(h2, r);
}

// ---------------------------------------------------------------------------
// Kernel 1 (fused): embeddings -> Xcat (f16), and Wih -> Wcat (f16).
// Blocks [0, B*S): embed position; blocks [B*S, B*S+NCOLS): weight row.
// Single f16 store per element (error ~6e-5 rms; dot-level ~1e-5 rms --
// R2 demonstrated absmax 2.4e-4 passes).
// ---------------------------------------------------------------------------
__global__ void embed_wcat(const int* __restrict__ word_ids,
                           const int* __restrict__ deps_ids,
                           const float* __restrict__ word_table,
                           const float* __restrict__ dep_table,
                           const float* __restrict__ Wih_f,
                           const float* __restrict__ Wih_b,
                           _Float16* __restrict__ Xcat,
                           _Float16* __restrict__ Wcat) {
    int blk = blockIdx.x;
    if (blk >= BATCH * S_LEN) {
        int n = blk - BATCH * S_LEN;
        const float* src = (n < NGATE) ? (Wih_f + (size_t)n * EDIM)
                                       : (Wih_b + (size_t)(n - NGATE) * EDIM);
        _Float16* wr = Wcat + (size_t)n * KPAD;
        for (int e = threadIdx.x; e < KPAD; e += 128)
            wr[e] = (_Float16)((e < EDIM) ? src[e] : 0.f);
        return;
    }
    int pos = blk;
    int b = pos >> 9, s = pos & (S_LEN - 1);
    int wid = word_ids[b * 3 * S_LEN + S_LEN + s];
    const int* dp = deps_ids + (size_t)pos * 8;
    int ids[8];
    int cnt = 0;
#pragma unroll
    for (int d = 0; d < 8; ++d) {
        int id = dp[d];
        ids[d] = id;
        cnt += (id != 0 && id != 1) ? 1 : 0;
    }
    float inv = 0.5f / (float)((cnt > 0) ? cnt : 1);
    const float* wr = word_table + (size_t)wid * EDIM;
    _Float16* xr = Xcat + (size_t)pos * KPAD;
    for (int e = threadIdx.x; e < KPAD; e += 128) {
        float v = 0.f;
        if (e < EDIM) {
            float w = wr[e];
            float dsum = 0.f;
#pragma unroll
            for (int d = 0; d < 8; ++d) {
                if (ids[d] != 0 && ids[d] != 1) dsum += dep_table[ids[d] * EDIM + e];
            }
            v = (cnt > 0) ? (0.5f * w + dsum * inv) : w;
        }
        xr[e] = (_Float16)v;
    }
}

// ---------------------------------------------------------------------------
// Kernel 2: MFMA GEMM, f16 single-pass (K=320, 10 k-iters; was 960/30).
// Same verified tile structure (128x128, 4 waves, LSTR=40 pad).
// ---------------------------------------------------------------------------
#define LSTR 40
__global__ __launch_bounds__(256) void gemm_mfma(
        const _Float16* __restrict__ Xcat,
        const _Float16* __restrict__ Wcat,
        const float* __restrict__ b_f, const float* __restrict__ b_b,
        float* __restrict__ pre) {
    __shared__ _Float16 Asub[128 * LSTR];
    __shared__ _Float16 Bsub[128 * LSTR];
    int tid = threadIdx.x;
    int wave = tid >> 6, lane = tid & 63;
    int lid = lane & 15, quad = lane >> 4;
    int m0 = blockIdx.x * 128, n0 = blockIdx.y * 128;
    int wm = (wave >> 1) * 64, wn = (wave & 1) * 64;

    f4v acc[4][4];
#pragma unroll
    for (int i = 0; i < 4; ++i)
#pragma unroll
        for (int j = 0; j < 4; ++j) acc[i][j] = (f4v)0.f;

    float bias[4];
#pragma unroll
    for (int nt = 0; nt < 4; ++nt) {
        int n = n0 + wn + nt * 16 + lid;
        bias[nt] = (n < NGATE) ? b_f[n] : b_b[n - NGATE];
    }

    int c0 = tid, c1 = tid + 256;
    const _Float16* aptr0 = Xcat + (size_t)(m0 + (c0 >> 2)) * KPAD + (c0 & 3) * 8;
    const _Float16* aptr1 = Xcat + (size_t)(m0 + (c1 >> 2)) * KPAD + (c1 & 3) * 8;
    const _Float16* bptr0 = Wcat + (size_t)(n0 + (c0 >> 2)) * KPAD + (c0 & 3) * 8;
    const _Float16* bptr1 = Wcat + (size_t)(n0 + (c1 >> 2)) * KPAD + (c1 & 3) * 8;
    int la0 = (c0 >> 2) * LSTR + (c0 & 3) * 8;
    int la1 = (c1 >> 2) * LSTR + (c1 & 3) * 8;

    half8 ra0 = *(const half8*)(aptr0);
    half8 ra1 = *(const half8*)(aptr1);
    half8 rb0 = *(const half8*)(bptr0);
    half8 rb1 = *(const half8*)(bptr1);

    for (int k0 = 0; k0 < KPAD; k0 += 32) {
        __syncthreads();
        *(half8*)&Asub[la0] = ra0;
        *(half8*)&Asub[la1] = ra1;
        *(half8*)&Bsub[la0] = rb0;
        *(half8*)&Bsub[la1] = rb1;
        __syncthreads();
        if (k0 + 32 < KPAD) {
            ra0 = *(const half8*)(aptr0 + k0 + 32);
            ra1 = *(const half8*)(aptr1 + k0 + 32);
            rb0 = *(const half8*)(bptr0 + k0 + 32);
            rb1 = *(const half8*)(bptr1 + k0 + 32);
        }
        half8 aF[4], bF[4];
#pragma unroll
        for (int mt = 0; mt < 4; ++mt)
            aF[mt] = *(const half8*)&Asub[(wm + mt * 16 + lid) * LSTR + quad * 8];
#pragma unroll
        for (int nt = 0; nt < 4; ++nt)
            bF[nt] = *(const half8*)&Bsub[(wn + nt * 16 + lid) * LSTR + quad * 8];
#pragma unroll
        for (int mt = 0; mt < 4; ++mt)
#pragma unroll
            for (int nt = 0; nt < 4; ++nt)
                acc[mt][nt] = __builtin_amdgcn_mfma_f32_16x16x32_f16(
                    aF[mt], bF[nt], acc[mt][nt], 0, 0, 0);
    }

#pragma unroll
    for (int mt = 0; mt < 4; ++mt)
#pragma unroll
        for (int nt = 0; nt < 4; ++nt) {
            int n = n0 + wn + nt * 16 + lid;
#pragma unroll
            for (int r = 0; r < 4; ++r) {
                int m = m0 + wm + mt * 16 + quad * 4 + r;
                pre[(size_t)m * NCOLS + n] = acc[mt][nt][r] + bias[nt];
            }
        }
}

// ---------------------------------------------------------------------------
// Kernel 3: LSTM recurrence v8 — EXACT revert to R3's verified 260us kernel.
// ---------------------------------------------------------------------------
__global__ __launch_bounds__(256, 1) void lstm_rec(
        const float* __restrict__ pre,
        const float* __restrict__ Whh_f, const float* __restrict__ Whh_b,
        float* __restrict__ pooled) {
    __shared__ _Float16 h_s[HDIM];
    int t = threadIdx.x;
    int lane = t & 63;
    int wv = t >> 6;
    int tau = lane & 3;
    int ks  = (lane >> 2) & 3;
    int hi2 = lane >> 4;
    int hbase = wv * 32 + hi2 * 8;          // hidx(j) = hbase + j
    int b = blockIdx.x >> 1;
    int dir = blockIdx.x & 1;
    const float* Whh = dir ? Whh_b : Whh_f;

    // f16 weights: w[j][q] = Whh[tau*128 + hbase+j][32ks + 2q, +1]  (128 VGPRs)
    h2 w[8][16];
#pragma unroll
    for (int j = 0; j < 8; ++j) {
        const float* rp = Whh + (size_t)(tau * HDIM + hbase + j) * HDIM + ks * 32;
#pragma unroll
        for (int q = 0; q < 16; ++q) w[j][q] = pk_f16(rp[2 * q], rp[2 * q + 1]);
    }

    float c = 0.f;
    float hmax = -1e30f;
    if (t < 64) ((uint*)h_s)[t] = 0u;       // zero 128 f16

    // owned pre columns: gates (tau, hbase+2ks) and (tau, hbase+2ks+1)
    const float* pX = pre + (size_t)b * S_LEN * NCOLS + dir * NGATE
                    + tau * HDIM + hbase + 2 * ks;
    const float* pY = pX + 1;
    int s = dir ? (S_LEN - 1) : 0;
    int sd = dir ? -1 : 1;
    float pXn1 = pX[(long)s * NCOLS], pYn1 = pY[(long)s * NCOLS];
    float pXn2 = pX[(long)(s + sd) * NCOLS], pYn2 = pY[(long)(s + sd) * NCOLS];

    int hZ = hbase + 2 * ks + (tau >> 1);   // hidx this lane's activation owns
    bool is_g = (tau == 2);
    float mult = is_g ? -2.f : -1.f;        // exp arg scale: sigm e^-g, tanh e^-2g
    float sA   = is_g ?  2.f :  1.f;        // act = fma(rcp, sA, sB)
    float sB   = is_g ? -1.f :  0.f;
    bool oy = (tau & 2) != 0;               // lanes tau>=2 consume the Y-set
    const h2* hp = (const h2*)h_s + ks * 16;

    asm volatile("s_waitcnt lgkmcnt(0)\n\ts_barrier" ::: "memory");

    for (int step = 0; step < S_LEN; ++step) {
        float curX = pXn1, curY = pYn1;
        pXn1 = pXn2; pYn1 = pYn2;
        if (step + 2 < S_LEN) {
            pXn2 = pX[(long)(s + 2 * sd) * NCOLS];
            pYn2 = pY[(long)(s + 2 * sd) * NCOLS];
        }

        // h slice for this lane's k-range: 16 h2 = 64 B = 4 x ds_read_b128
        h2 hh[16];
#pragma unroll
        for (int q = 0; q < 16; ++q) hh[q] = hp[q];

        // 8 partial dots over the owned k-slice (8 independent chains)
        float P[8];
#pragma unroll
        for (int j = 0; j < 8; ++j) {
            float acc = 0.f;
#pragma unroll
            for (int q = 0; q < 16; ++q)
                acc = __builtin_amdgcn_fdot2(w[j][q], hh[q], acc, false);
            P[j] = acc;
        }

        // fused k-combine across the 4 ks lanes: 16 single-instr dpp-adds.
        float R0 = P[0], R1 = P[1], R2 = P[2], R3 = P[3];
        float R4 = P[4], R5 = P[5], R6 = P[6], R7 = P[7];
        asm("s_nop 1\n\t"
            "v_add_f32_dpp %0, %0, %0 row_ror:4 row_mask:0xf bank_mask:0xf\n\t"
            "v_add_f32_dpp %1, %1, %1 row_ror:4 row_mask:0xf bank_mask:0xf\n\t"
            "v_add_f32_dpp %2, %2, %2 row_ror:4 row_mask:0xf bank_mask:0xf\n\t"
            "v_add_f32_dpp %3, %3, %3 row_ror:4 row_mask:0xf bank_mask:0xf\n\t"
            "v_add_f32_dpp %4, %4, %4 row_ror:4 row_mask:0xf bank_mask:0xf\n\t"
            "v_add_f32_dpp %5, %5, %5 row_ror:4 row_mask:0xf bank_mask:0xf\n\t"
            "v_add_f32_dpp %6, %6, %6 row_ror:4 row_mask:0xf bank_mask:0xf\n\t"
            "v_add_f32_dpp %7, %7, %7 row_ror:4 row_mask:0xf bank_mask:0xf\n\t"
            "v_add_f32_dpp %0, %0, %0 row_ror:8 row_mask:0xf bank_mask:0xf\n\t"
            "v_add_f32_dpp %1, %1, %1 row_ror:8 row_mask:0xf bank_mask:0xf\n\t"
            "v_add_f32_dpp %2, %2, %2 row_ror:8 row_mask:0xf bank_mask:0xf\n\t"
            "v_add_f32_dpp %3, %3, %3 row_ror:8 row_mask:0xf bank_mask:0xf\n\t"
            "v_add_f32_dpp %4, %4, %4 row_ror:8 row_mask:0xf bank_mask:0xf\n\t"
            "v_add_f32_dpp %5, %5, %5 row_ror:8 row_mask:0xf bank_mask:0xf\n\t"
            "v_add_f32_dpp %6, %6, %6 row_ror:8 row_mask:0xf bank_mask:0xf\n\t"
            "v_add_f32_dpp %7, %7, %7 row_ror:8 row_mask:0xf bank_mask:0xf"
            : "+v"(R0), "+v"(R1), "+v"(R2), "+v"(R3),
              "+v"(R4), "+v"(R5), "+v"(R6), "+v"(R7));

        // this lane's two owned raw gates (j = 2ks, 2ks+1)
        float X01 = (ks & 1) ? R2 : R0;
        float X23 = (ks & 1) ? R6 : R4;
        float X   = (ks & 2) ? X23 : X01;
        float Y01 = (ks & 1) ? R3 : R1;
        float Y23 = (ks & 1) ? R7 : R5;
        float Y   = (ks & 2) ? Y23 : Y01;
        float gX = X + curX;
        float gY = Y + curY;

        // activate locally (both gates are type tau): exact v6 math.
        float eX = __expf(gX * mult);
        float eY = __expf(gY * mult);
        float rX = __builtin_amdgcn_rcpf(1.f + eX);
        float rY = __builtin_amdgcn_rcpf(1.f + eY);
        float actX = fmaf(rX, sA, sB);
        float actY = fmaf(rY, sA, sB);

        // quad broadcasts of ACTIVATED gates: 8 single-instr mov_dpp.
        float aiX, afX, agX, aoX, aiY, afY, agY, aoY;
        asm("s_nop 1\n\t"
            "v_mov_b32_dpp %0, %8 quad_perm:[0,0,0,0] row_mask:0xf bank_mask:0xf\n\t"
            "v_mov_b32_dpp %4, %9 quad_perm:[0,0,0,0] row_mask:0xf bank_mask:0xf\n\t"
            "v_mov_b32_dpp %1, %8 quad_perm:[1,1,1,1] row_mask:0xf bank_mask:0xf\n\t"
            "v_mov_b32_dpp %5, %9 quad_perm:[1,1,1,1] row_mask:0xf bank_mask:0xf\n\t"
            "v_mov_b32_dpp %2, %8 quad_perm:[2,2,2,2] row_mask:0xf bank_mask:0xf\n\t"
            "v_mov_b32_dpp %6, %9 quad_perm:[2,2,2,2] row_mask:0xf bank_mask:0xf\n\t"
            "v_mov_b32_dpp %3, %8 quad_perm:[3,3,3,3] row_mask:0xf bank_mask:0xf\n\t"
            "v_mov_b32_dpp %7, %9 quad_perm:[3,3,3,3] row_mask:0xf bank_mask:0xf"
            : "=&v"(aiX), "=&v"(afX), "=&v"(agX), "=&v"(aoX),
              "=&v"(aiY), "=&v"(afY), "=&v"(agY), "=&v"(aoY)
            : "v"(actX), "v"(actY));

        // lanes tau<2 consume X-set (hidx hA), tau>=2 the Y-set (hA+1)
        float ai = oy ? aiY : aiX;
        float af = oy ? afY : afX;
        float ag = oy ? agY : agX;
        float ao = oy ? aoY : aoX;

        c = fmaf(af, c, ai * ag);
        float ec = __expf(-2.f * c);
        float rc = __builtin_amdgcn_rcpf(1.f + ec);
        float h  = ao * fmaf(rc, 2.f, -1.f);   // ao * tanh(c)
        hmax = fmaxf(hmax, h);

        if ((tau & 1) == 0) h_s[hZ] = (_Float16)h;   // tau 0 & 2 write
        asm volatile("s_waitcnt lgkmcnt(0)\n\ts_barrier" ::: "memory");
        s += sd;
    }

    if ((tau & 1) == 0) pooled[b * 256 + dir * HDIM + hZ] = hmax;
}

// ---------------------------------------------------------------------------
// Kernel 4: classifier (unchanged)
// ---------------------------------------------------------------------------
__global__ void cls_kernel(const float* __restrict__ pooled,
                           const float* __restrict__ W_cls,
                           const float* __restrict__ b_cls,
                           float* __restrict__ out) {
    int i = threadIdx.x;
    if (i < BATCH * 5) {
        int b = i / 5, l = i % 5;
        float acc = b_cls[l];
        const float* p = pooled + b * 256;
        const float* w = W_cls + l * 256;
#pragma unroll 8
        for (int j = 0; j < 256; ++j) acc = fmaf(p[j], w[j], acc);
        out[i] = acc;
    }
}

// ---------------------------------------------------------------------------
extern "C" void kernel_launch(void* const* d_in, const int* in_sizes, int n_in,
                              void* d_out, int out_size, void* d_ws, size_t ws_size,
                              hipStream_t stream) {
    const int*   word_ids   = (const int*)d_in[0];
    const int*   deps_ids   = (const int*)d_in[1];
    const float* word_table = (const float*)d_in[2];
    const float* dep_table  = (const float*)d_in[3];
    const float* Wih_f      = (const float*)d_in[4];
    const float* Whh_f      = (const float*)d_in[5];
    const float* b_f        = (const float*)d_in[6];
    const float* Wih_b      = (const float*)d_in[7];
    const float* Whh_b      = (const float*)d_in[8];
    const float* b_b        = (const float*)d_in[9];
    const float* W_cls      = (const float*)d_in[10];
    const float* b_cls      = (const float*)d_in[11];
    float* out = (float*)d_out;

    float*     pre    = (float*)d_ws;
    float*     pooled = pre + (size_t)BATCH * S_LEN * NCOLS;
    _Float16*  Xcat   = (_Float16*)(pooled + BATCH * 256);
    _Float16*  Wcat   = Xcat + (size_t)BATCH * S_LEN * KPAD;

    embed_wcat<<<BATCH * S_LEN + NCOLS, 128, 0, stream>>>(
        word_ids, deps_ids, word_table, dep_table, Wih_f, Wih_b, Xcat, Wcat);
    gemm_mfma<<<dim3(128, 8), 256, 0, stream>>>(Xcat, Wcat, b_f, b_b, pre);
    lstm_rec<<<64, 256, 0, stream>>>(pre, Whh_f, Whh_b, pooled);
    cls_kernel<<<1, 192, 0, stream>>>(pooled, W_cls, b_cls, out);
}